// Round 3
// baseline (125.442 us; speedup 1.0000x reference)
//
#include <hip/hip_runtime.h>

// (B,N,D,H) = (4, 2048, 1024, 64)
constexpr int kN = 2048;
constexpr int kD = 1024;

typedef __attribute__((ext_vector_type(8))) short bf16x8;
typedef __attribute__((ext_vector_type(4))) short bf16x4;
typedef __attribute__((ext_vector_type(4))) float f32x4;

#define MFMA(a, b, c) __builtin_amdgcn_mfma_f32_16x16x32_bf16(a, b, c, 0, 0, 0)

// exp(s/8) == exp2(s * log2(e)/8); single mul feeding v_exp_f32.
// MUST be the same constant in stats and out so keep-sets stay bit-identical.
constexpr float kExpC = 0.18033688011112042f;
#define EXP8(sv) __builtin_amdgcn_exp2f((sv) * kExpC)

__device__ __forceinline__ short f2bf(float f) {
    unsigned u = __float_as_uint(f);
    u += 0x7fff + ((u >> 16) & 1);      // round-to-nearest-even
    return (short)(u >> 16);
}

// ---------------------------------------------------------------------------
// prep: Wt in MFMA-fragment-contiguous layout (unchanged).
// ---------------------------------------------------------------------------
__global__ __launch_bounds__(256) void prep_kernel(
        const float* __restrict__ Wq, const float* __restrict__ Wk,
        const float* __restrict__ Wv, const float* __restrict__ bq,
        const float* __restrict__ bk, const float* __restrict__ bv,
        short* __restrict__ Wt, float* __restrict__ bcat)
{
    int tid = blockIdx.x * 256 + threadIdx.x;
    int stride = gridDim.x * 256;
    for (int e = tid; e < 16 * 12 * 2 * 512; e += stride) {
        int kc = e / 12288;
        int rem = e - kc * 12288;
        int nt = rem >> 10;
        int r2 = rem & 1023;
        int f = r2 >> 9;
        int r3 = r2 & 511;
        int q8 = r3 >> 7;
        int l15 = (r3 >> 3) & 15;
        int el = r3 & 7;
        int n = nt * 16 + l15;
        int d = kc * 64 + f * 32 + q8 * 8 + el;
        float wv = (n < 64) ? Wq[d * 64 + n]
                 : (n < 128) ? Wk[d * 64 + (n - 64)]
                 : Wv[d * 64 + (n - 128)];
        Wt[e] = f2bf(wv);
    }
    if (tid < 192)
        bcat[tid] = (tid < 64) ? bq[tid] : (tid < 128) ? bk[tid - 64] : bv[tid - 128];
}

// ---------------------------------------------------------------------------
// qkv (unchanged): [8192x1024]@[1024x192]. Near its BW floor:
// x HBM 33.5MB ~5.3us overlapped with Wt L2 196MB ~5.7us via 2 blocks/CU.
// ---------------------------------------------------------------------------
constexpr int XP = 1032;   // xs pitch (shorts): stride 516 words = 4 mod 32 banks

__global__ __launch_bounds__(256) void qkv_kernel(
        const float* __restrict__ x, const short* __restrict__ Wt,
        const float* __restrict__ bcat,
        short* __restrict__ gq, short* __restrict__ gk, short* __restrict__ vt)
{
    __shared__ __align__(16) short xs[16 * XP];    // 33,024 B
    const int t = threadIdx.x;
    const int w = t >> 6, lane = t & 63, l15 = lane & 15, q8 = lane >> 4;
    const int m0 = blockIdx.x * 16;

    {
        int row = t >> 4, c4 = (t & 15) * 4;
        const float* xr = x + (size_t)(m0 + row) * kD;
        #pragma unroll
        for (int cc = 0; cc < 16; ++cc) {
            float4 xv = *(const float4*)&xr[cc * 64 + c4];
            bf16x4 pk = {f2bf(xv.x), f2bf(xv.y), f2bf(xv.z), f2bf(xv.w)};
            *(bf16x4*)&xs[row * XP + cc * 64 + c4] = pk;
        }
    }
    __syncthreads();

    f32x4 acc[3];
    #pragma unroll
    for (int ct = 0; ct < 3; ++ct) acc[ct] = (f32x4){0.f, 0.f, 0.f, 0.f};

    #pragma unroll 4
    for (int kc = 0; kc < 16; ++kc) {
        bf16x8 a0 = *(const bf16x8*)&xs[l15 * XP + kc * 64 + q8 * 8];
        bf16x8 a1 = *(const bf16x8*)&xs[l15 * XP + kc * 64 + 32 + q8 * 8];
        #pragma unroll
        for (int ct = 0; ct < 3; ++ct) {
            int nt = w * 3 + ct;
            const short* bp = Wt + ((size_t)(kc * 12 + nt) * 2) * 512 + lane * 8;
            bf16x8 b0 = *(const bf16x8*)bp;
            bf16x8 b1 = *(const bf16x8*)(bp + 512);
            acc[ct] = MFMA(a0, b0, acc[ct]);
            acc[ct] = MFMA(a1, b1, acc[ct]);
        }
    }

    const int bz = m0 >> 11;
    const int jt = (m0 & 2047) >> 6;
    const int jb = m0 & 63;                // 0/16/32/48
    #pragma unroll
    for (int ct = 0; ct < 3; ++ct) {
        int nb2 = w * 48 + ct * 16;        // 16-tile lies in one region
        int n = nb2 + l15;
        float bias = bcat[n];
        if (nb2 < 64) {
            #pragma unroll
            for (int r = 0; r < 4; ++r)
                gq[(size_t)(m0 + q8 * 4 + r) * 72 + n] = f2bf(acc[ct][r] + bias);
        } else if (nb2 < 128) {
            #pragma unroll
            for (int r = 0; r < 4; ++r)
                gk[(size_t)(m0 + q8 * 4 + r) * 72 + (n - 64)] = f2bf(acc[ct][r] + bias);
        } else {
            int h = n - 128;
            bf16x4 pk = {f2bf(acc[ct][0] + bias), f2bf(acc[ct][1] + bias),
                         f2bf(acc[ct][2] + bias), f2bf(acc[ct][3] + bias)};
            *(bf16x4*)&vt[((size_t)((bz * 32 + jt) * 64 + h)) * 72 + jb + q8 * 4] = pk;
        }
    }
}

// ---------------------------------------------------------------------------
// stats: l[j] = sum_{i>=j, s!=0} exp(s/8).
// v3: ZERO LDS, ZERO barriers. K fragments loaded direct from global: all 4
//     waves of a block read IDENTICAL rows -> L1 serves 3 of 4. ic split
//     8 x 256 (grid 1024): max 4 iterations, better balance + latency hiding.
// ---------------------------------------------------------------------------
__global__ __launch_bounds__(256) void stats_kernel(
        const short* __restrict__ gq, const short* __restrict__ gk,
        float* __restrict__ l2)
{
    const int t = threadIdx.x;
    const int w = t >> 6, lane = t & 63, l15 = lane & 15, q8 = lane >> 4;
    const int b = blockIdx.x;
    const int ic = b & 7, bz = (b >> 3) & 3, jt = b >> 5;
    const int j0 = jt * 64;
    const int ilo = ic * 256, ihi = ilo + 256;
    const int istart = (j0 > ilo) ? j0 : ilo;
    const int count = (istart < ihi) ? ((ihi - istart) >> 6) : 0;

    float lloc[4] = {0.f, 0.f, 0.f, 0.f};

    if (count > 0) {
        const short* qp = gq + (size_t)(bz * kN + j0 + 16 * w + l15) * 72 + q8 * 8;
        bf16x8 a0 = *(const bf16x8*)qp;
        bf16x8 a1 = *(const bf16x8*)(qp + 32);

        for (int idx = 0; idx < count; ++idx) {
            const int i0 = istart + idx * 64;
            const short* kp = gk + (size_t)(bz * kN + i0 + l15) * 72 + q8 * 8;
            #pragma unroll
            for (int it = 0; it < 4; ++it) {
                bf16x8 b0 = *(const bf16x8*)(kp + (size_t)(it * 16) * 72);
                bf16x8 b1 = *(const bf16x8*)(kp + (size_t)(it * 16) * 72 + 32);
                f32x4 s = (f32x4){0.f, 0.f, 0.f, 0.f};
                s = MFMA(a0, b0, s);
                s = MFMA(a1, b1, s);
                int ig = i0 + it * 16 + l15;
                if (i0 + it * 16 >= j0 + 16 * w + 15) {
                    // whole sub-tile satisfies ig >= jg (wave-uniform)
                    #pragma unroll
                    for (int r = 0; r < 4; ++r) {
                        float sv = s[r];
                        lloc[r] += (sv != 0.0f) ? EXP8(sv) : 0.0f;
                    }
                } else {
                    #pragma unroll
                    for (int r = 0; r < 4; ++r) {
                        int jg = j0 + 16 * w + q8 * 4 + r;
                        float sv = s[r];
                        lloc[r] += ((ig >= jg) && (sv != 0.0f)) ? EXP8(sv) : 0.0f;
                    }
                }
            }
        }
    }
    #pragma unroll
    for (int off = 1; off < 16; off <<= 1)
        #pragma unroll
        for (int r = 0; r < 4; ++r)
            lloc[r] += __shfl_xor(lloc[r], off);
    if (l15 == 0) {
        #pragma unroll
        for (int r = 0; r < 4; ++r)
            l2[ic * 8192 + bz * kN + j0 + 16 * w + q8 * 4 + r] = lloc[r];
    }
}

// ---------------------------------------------------------------------------
// out: partial[i,h] = sum_{j in jc-chunk, j<=i} (exp(s/8)/l[j]) * v[j,h]
// v3: - vsm dropped: V fragments direct from global (4 waves read identical
//       rows -> L1 shared); barriers no longer drain any DMA prefetch.
//     - LDS 29.7 -> 11.3 KB (psm + rsm only).
//     - count==0 blocks exit without writing part (reduce skips them).
// ---------------------------------------------------------------------------
__global__ __launch_bounds__(256) void out_kernel(
        const short* __restrict__ gq, const short* __restrict__ gk,
        const short* __restrict__ vt, const float* __restrict__ l2,
        float* __restrict__ part)
{
    __shared__ __align__(16) short psm[64 * 72];
    __shared__ __align__(16) float rsm[512];
    const int t = threadIdx.x;
    const int w = t >> 6, lane = t & 63, l15 = lane & 15, q8 = lane >> 4;
    const int b = blockIdx.x;
    const int jc = b & 3, bz = (b >> 2) & 3, it = b >> 4;
    const int i0 = it * 64;
    const int jlo = jc * 512;
    const int jhi = (jlo + 512 < i0 + 64) ? (jlo + 512) : (i0 + 64);
    const int count = (jlo < jhi) ? ((jhi - jlo) >> 6) : 0;
    if (count == 0) return;    // block-uniform; reduce skips this slice

    // reciprocal softmax denominators for this block's j-range (512 entries)
    for (int jj = t; jj < 512; jj += 256) {
        int j = bz * kN + jlo + jj;
        float l = 0.f;
        #pragma unroll
        for (int c = 0; c < 8; ++c) l += l2[c * 8192 + j];
        rsm[jj] = (l > 0.f) ? 1.0f / l : 0.0f;
    }

    f32x4 oacc[4];
    #pragma unroll
    for (int i = 0; i < 4; ++i) oacc[i] = (f32x4){0.f, 0.f, 0.f, 0.f};

    // K fragments: loop-invariant for the whole block -> registers
    bf16x8 kb0[4], kb1[4];
    #pragma unroll
    for (int itile = 0; itile < 4; ++itile) {
        const short* kp = gk + (size_t)(bz * kN + i0 + itile * 16 + l15) * 72 + q8 * 8;
        kb0[itile] = *(const bf16x8*)kp;
        kb1[itile] = *(const bf16x8*)(kp + 32);
    }
    const short* qp = gq + (size_t)(bz * kN + jlo + 16 * w + l15) * 72 + q8 * 8;
    bf16x8 qa0 = *(const bf16x8*)qp;
    bf16x8 qa1 = *(const bf16x8*)(qp + 32);
    __syncthreads();       // rsm ready

    for (int idx = 0; idx < count; ++idx) {
        const int j0s = jlo + idx * 64;
        const bool more = (idx + 1 < count);

        // V fragments for this iteration: direct global loads (issue early,
        // land during S phase; all 4 waves hit the same lines -> L1)
        const short* vp = vt + (size_t)((bz * 32 + (j0s >> 6)) * 64 + l15) * 72 + q8 * 8;
        bf16x8 vb0[4], vb1[4];
        #pragma unroll
        for (int ht = 0; ht < 4; ++ht) {
            vb0[ht] = *(const bf16x8*)(vp + (size_t)(ht * 16) * 72);
            vb1[ht] = *(const bf16x8*)(vp + (size_t)(ht * 16) * 72 + 32);
        }
        bf16x8 qn0, qn1;
        if (more) {
            const short* qn =
                gq + (size_t)(bz * kN + j0s + 64 + 16 * w + l15) * 72 + q8 * 8;
            qn0 = *(const bf16x8*)qn;
            qn1 = *(const bf16x8*)(qn + 32);
        }
        // rl for this iteration's 4 j's (broadcast within 16-lane groups)
        f32x4 rl4 = *(const f32x4*)&rsm[(j0s - jlo) + 16 * w + q8 * 4];

        // S phase (bit-identical MFMA sequence to stats)
        #pragma unroll
        for (int itile = 0; itile < 4; ++itile) {
            f32x4 s = (f32x4){0.f, 0.f, 0.f, 0.f};
            s = MFMA(qa0, kb0[itile], s);
            s = MFMA(qa1, kb1[itile], s);
            int ig = i0 + itile * 16 + l15;
            bf16x4 pk;
            if (i0 + itile * 16 >= j0s + 16 * w + 15) {
                #pragma unroll
                for (int r = 0; r < 4; ++r) {
                    float sv = s[r];
                    float p = (sv != 0.0f) ? EXP8(sv) * rl4[r] : 0.0f;
                    pk[r] = f2bf(p);
                }
            } else {
                #pragma unroll
                for (int r = 0; r < 4; ++r) {
                    int jg = j0s + 16 * w + q8 * 4 + r;
                    float sv = s[r];
                    float p = ((ig >= jg) && (sv != 0.0f))
                              ? EXP8(sv) * rl4[r] : 0.0f;
                    pk[r] = f2bf(p);
                }
            }
            *(bf16x4*)&psm[(itile * 16 + l15) * 72 + 16 * w + q8 * 4] = pk;
        }
        __syncthreads();   // psm ready (only LDS waits matter now)

        // PV phase: A = psm[i-local][j], B = V fragments (registers)
        bf16x8 pa0 = *(const bf16x8*)&psm[(16 * w + l15) * 72 + q8 * 8];
        bf16x8 pa1 = *(const bf16x8*)&psm[(16 * w + l15) * 72 + 32 + q8 * 8];
        #pragma unroll
        for (int ht = 0; ht < 4; ++ht) {
            oacc[ht] = MFMA(pa0, vb0[ht], oacc[ht]);
            oacc[ht] = MFMA(pa1, vb1[ht], oacc[ht]);
        }
        __syncthreads();   // protect psm before next S overwrites it
        if (more) { qa0 = qn0; qa1 = qn1; }
    }

    size_t base = ((size_t)(jc * 4 + bz) * kN + i0) * 64;
    #pragma unroll
    for (int ht = 0; ht < 4; ++ht)
        #pragma unroll
        for (int r = 0; r < 4; ++r)
            part[base + (size_t)(16 * w + q8 * 4 + r) * 64 + ht * 16 + l15] = oacc[ht][r];
}

// ---------------------------------------------------------------------------
// reduce: out = sum of the VALID jc-chunk partials only.
// Chunk jc valid for row i iff jc < (i>>9)+1 (matches out's count>0 set).
// ---------------------------------------------------------------------------
__global__ __launch_bounds__(256) void reduce_kernel(
        const float* __restrict__ part, float* __restrict__ out)
{
    int idx = blockIdx.x * 256 + threadIdx.x;     // 0..131071 float4s
    int i = (idx >> 4) & 2047;                    // row within [bz][2048][64]
    int nvalid = (i >> 9) + 1;                    // 1..4
    const float4* p = (const float4*)part;
    float4 r = p[idx];
    for (int c = 1; c < nvalid; ++c) {
        float4 v = p[idx + c * 131072];
        r.x += v.x; r.y += v.y; r.z += v.z; r.w += v.w;
    }
    ((float4*)out)[idx] = r;
}

extern "C" void kernel_launch(void* const* d_in, const int* in_sizes, int n_in,
                              void* d_out, int out_size, void* d_ws, size_t ws_size,
                              hipStream_t stream)
{
    const float* x  = (const float*)d_in[0];
    const float* Wq = (const float*)d_in[1];
    const float* bq = (const float*)d_in[2];
    const float* Wk = (const float*)d_in[3];
    const float* bk = (const float*)d_in[4];
    const float* Wv = (const float*)d_in[5];
    const float* bv = (const float*)d_in[6];
    float* out = (float*)d_out;

    char* base = (char*)d_ws;
    short* Wt   = (short*)(base);                    //    393,216 B
    float* bcat = (float*)(base + 393216);           //      1,024 B
    short* gq   = (short*)(base + 394240);           //  1,179,648 B
    short* gk   = (short*)(base + 1573888);          //  1,179,648 B
    short* vt   = (short*)(base + 2753536);          //  1,179,648 B
    float* l2   = (float*)(base + 3933184);          //    262,144 B (8 slices)
    float* part = (float*)(base + 4195328);          //  8,388,608 B

    prep_kernel<<<256, 256, 0, stream>>>(Wq, Wk, Wv, bq, bk, bv, Wt, bcat);
    qkv_kernel<<<512, 256, 0, stream>>>(x, Wt, bcat, gq, gk, vt);
    stats_kernel<<<1024, 256, 0, stream>>>(gq, gk, l2);
    out_kernel<<<512, 256, 0, stream>>>(gq, gk, vt, l2, part);
    reduce_kernel<<<512, 256, 0, stream>>>(part, out);
}

// Round 4
// 122.077 us; speedup vs baseline: 1.0276x; 1.0276x over previous
//
#include <hip/hip_runtime.h>

// (B,N,D,H) = (4, 2048, 1024, 64)
constexpr int kN = 2048;
constexpr int kD = 1024;

typedef __attribute__((ext_vector_type(8))) short bf16x8;
typedef __attribute__((ext_vector_type(4))) short bf16x4;
typedef __attribute__((ext_vector_type(4))) float f32x4;

#define MFMA(a, b, c) __builtin_amdgcn_mfma_f32_16x16x32_bf16(a, b, c, 0, 0, 0)

// exp(s/8) == exp2(s * log2(e)/8); single mul feeding v_exp_f32.
// MUST be the same constant in stats and out so keep-sets stay bit-identical.
constexpr float kExpC = 0.18033688011112042f;
#define EXP8(sv) __builtin_amdgcn_exp2f((sv) * kExpC)

__device__ __forceinline__ short f2bf(float f) {
    unsigned u = __float_as_uint(f);
    u += 0x7fff + ((u >> 16) & 1);      // round-to-nearest-even
    return (short)(u >> 16);
}

// global->LDS direct DMA. LDS dest = wave-uniform base + lane*16.
__device__ __forceinline__ void g2l(void* lds, const void* g, int nbytes, int t) {
    int lane = t & 63, w = t >> 6;
    for (int base = w * 1024; base < nbytes; base += 4096) {
        if (base + lane * 16 < nbytes) {
            __builtin_amdgcn_global_load_lds(
                (const __attribute__((address_space(1))) void*)((const char*)g + base + lane * 16),
                (__attribute__((address_space(3))) void*)((char*)lds + base),
                16, 0, 0);
        }
    }
}

// ---------------------------------------------------------------------------
// prep v2: grid 192 = (kc 0..15) x (nt 0..11); block-uniform region select,
// pure bit-op per-thread indexing (old version burned ~20 VALU/element on
// div/mod chains). Each thread: 4 gather loads + one 8B store.
//   e = b*1024 + 4t + j ; f=t>>7, q8=(t>>5)&3, l15=(t>>1)&15, el=(t&1)*4+j
//   n = nt*16+l15, d = kc*64 + f*32 + q8*8 + el
// ---------------------------------------------------------------------------
__global__ __launch_bounds__(256) void prep_kernel(
        const float* __restrict__ Wq, const float* __restrict__ Wk,
        const float* __restrict__ Wv, const float* __restrict__ bq,
        const float* __restrict__ bk, const float* __restrict__ bv,
        short* __restrict__ Wt, float* __restrict__ bcat)
{
    const int b = blockIdx.x;          // 0..191
    const int kc = b / 12;             // scalar magic-mul
    const int nt = b - kc * 12;
    const int t = threadIdx.x;
    const int f = t >> 7, q8 = (t >> 5) & 3, l15 = (t >> 1) & 15;
    const int elb = (t & 1) * 4;

    const int region = nt >> 2;        // 0=q, 1=k, 2=v (block-uniform)
    const float* __restrict__ W = (region == 0) ? Wq : (region == 1) ? Wk : Wv;
    const int col = (nt & 3) * 16 + l15;
    const int d0 = kc * 64 + f * 32 + q8 * 8 + elb;

    bf16x4 pk;
    #pragma unroll
    for (int j = 0; j < 4; ++j)
        pk[j] = f2bf(W[(size_t)(d0 + j) * 64 + col]);
    *(bf16x4*)&Wt[(size_t)b * 1024 + t * 4] = pk;

    if (b == 0 && t < 192)
        bcat[t] = (t < 64) ? bq[t] : (t < 128) ? bk[t - 64] : bv[t - 128];
}

// ---------------------------------------------------------------------------
// qkv (unchanged): [8192x1024]@[1024x192]. Near its BW floor:
// x HBM 33.5MB ~5.3us overlapped with Wt L2 196MB ~5.7us via multi-block/CU.
// ---------------------------------------------------------------------------
constexpr int XP = 1032;   // xs pitch (shorts): stride 516 words = 4 mod 32 banks

__global__ __launch_bounds__(256) void qkv_kernel(
        const float* __restrict__ x, const short* __restrict__ Wt,
        const float* __restrict__ bcat,
        short* __restrict__ gq, short* __restrict__ gk, short* __restrict__ vt)
{
    __shared__ __align__(16) short xs[16 * XP];    // 33,024 B
    const int t = threadIdx.x;
    const int w = t >> 6, lane = t & 63, l15 = lane & 15, q8 = lane >> 4;
    const int m0 = blockIdx.x * 16;

    {
        int row = t >> 4, c4 = (t & 15) * 4;
        const float* xr = x + (size_t)(m0 + row) * kD;
        #pragma unroll
        for (int cc = 0; cc < 16; ++cc) {
            float4 xv = *(const float4*)&xr[cc * 64 + c4];
            bf16x4 pk = {f2bf(xv.x), f2bf(xv.y), f2bf(xv.z), f2bf(xv.w)};
            *(bf16x4*)&xs[row * XP + cc * 64 + c4] = pk;
        }
    }
    __syncthreads();

    f32x4 acc[3];
    #pragma unroll
    for (int ct = 0; ct < 3; ++ct) acc[ct] = (f32x4){0.f, 0.f, 0.f, 0.f};

    #pragma unroll 4
    for (int kc = 0; kc < 16; ++kc) {
        bf16x8 a0 = *(const bf16x8*)&xs[l15 * XP + kc * 64 + q8 * 8];
        bf16x8 a1 = *(const bf16x8*)&xs[l15 * XP + kc * 64 + 32 + q8 * 8];
        #pragma unroll
        for (int ct = 0; ct < 3; ++ct) {
            int nt = w * 3 + ct;
            const short* bp = Wt + ((size_t)(kc * 12 + nt) * 2) * 512 + lane * 8;
            bf16x8 b0 = *(const bf16x8*)bp;
            bf16x8 b1 = *(const bf16x8*)(bp + 512);
            acc[ct] = MFMA(a0, b0, acc[ct]);
            acc[ct] = MFMA(a1, b1, acc[ct]);
        }
    }

    const int bz = m0 >> 11;
    const int jt = (m0 & 2047) >> 6;
    const int jb = m0 & 63;                // 0/16/32/48
    #pragma unroll
    for (int ct = 0; ct < 3; ++ct) {
        int nb2 = w * 48 + ct * 16;        // 16-tile lies in one region
        int n = nb2 + l15;
        float bias = bcat[n];
        if (nb2 < 64) {
            #pragma unroll
            for (int r = 0; r < 4; ++r)
                gq[(size_t)(m0 + q8 * 4 + r) * 72 + n] = f2bf(acc[ct][r] + bias);
        } else if (nb2 < 128) {
            #pragma unroll
            for (int r = 0; r < 4; ++r)
                gk[(size_t)(m0 + q8 * 4 + r) * 72 + (n - 64)] = f2bf(acc[ct][r] + bias);
        } else {
            int h = n - 128;
            bf16x4 pk = {f2bf(acc[ct][0] + bias), f2bf(acc[ct][1] + bias),
                         f2bf(acc[ct][2] + bias), f2bf(acc[ct][3] + bias)};
            *(bf16x4*)&vt[((size_t)((bz * 32 + jt) * 64 + h)) * 72 + jb + q8 * 4] = pk;
        }
    }
}

// ---------------------------------------------------------------------------
// stats (round-2 measured-best form): l[j] = sum_{i>=j, s!=0} exp(s/8).
// g2l double-buffered ksm; Q direct from L2 (wave-private rows); interior
// uniform branch; exp2 single-mul. LDS 18.4 KB, zero-drain overlap via dbuf.
// ---------------------------------------------------------------------------
__global__ __launch_bounds__(256) void stats_kernel(
        const short* __restrict__ gq, const short* __restrict__ gk,
        float* __restrict__ l2)
{
    __shared__ __align__(16) short ksm[2][64 * 72];
    const int t = threadIdx.x;
    const int w = t >> 6, lane = t & 63, l15 = lane & 15, q8 = lane >> 4;
    const int b = blockIdx.x;
    const int ic = b & 3, bz = (b >> 2) & 3, jt = b >> 4;
    const int j0 = jt * 64;
    const int ilo = ic * 512, ihi = ilo + 512;
    const int istart = (j0 > ilo) ? j0 : ilo;
    const int count = (istart < ihi) ? ((ihi - istart) >> 6) : 0;

    float lloc[4] = {0.f, 0.f, 0.f, 0.f};

    if (count > 0) {
        const short* qp = gq + (size_t)(bz * kN + j0 + 16 * w + l15) * 72 + q8 * 8;
        bf16x8 a0 = *(const bf16x8*)qp;
        bf16x8 a1 = *(const bf16x8*)(qp + 32);
        g2l(ksm[0], gk + (size_t)(bz * kN + istart) * 72, 64 * 144, t);
        __syncthreads();

        for (int idx = 0; idx < count; ++idx) {
            const int cur = idx & 1;
            if (idx + 1 < count)
                g2l(ksm[cur ^ 1],
                    gk + (size_t)(bz * kN + istart + (idx + 1) * 64) * 72, 64 * 144, t);
            const int i0 = istart + idx * 64;
            #pragma unroll
            for (int it = 0; it < 4; ++it) {
                int irow = it * 16 + l15;
                bf16x8 b0 = *(const bf16x8*)&ksm[cur][irow * 72 + q8 * 8];
                bf16x8 b1 = *(const bf16x8*)&ksm[cur][irow * 72 + 32 + q8 * 8];
                f32x4 s = (f32x4){0.f, 0.f, 0.f, 0.f};
                s = MFMA(a0, b0, s);
                s = MFMA(a1, b1, s);
                int ig = i0 + it * 16 + l15;
                if (i0 + it * 16 >= j0 + 16 * w + 15) {
                    // whole sub-tile satisfies ig >= jg (wave-uniform)
                    #pragma unroll
                    for (int r = 0; r < 4; ++r) {
                        float sv = s[r];
                        lloc[r] += (sv != 0.0f) ? EXP8(sv) : 0.0f;
                    }
                } else {
                    #pragma unroll
                    for (int r = 0; r < 4; ++r) {
                        int jg = j0 + 16 * w + q8 * 4 + r;
                        float sv = s[r];
                        lloc[r] += ((ig >= jg) && (sv != 0.0f)) ? EXP8(sv) : 0.0f;
                    }
                }
            }
            __syncthreads();
        }
    }
    #pragma unroll
    for (int off = 1; off < 16; off <<= 1)
        #pragma unroll
        for (int r = 0; r < 4; ++r)
            lloc[r] += __shfl_xor(lloc[r], off);
    if (l15 == 0) {
        #pragma unroll
        for (int r = 0; r < 4; ++r)
            l2[ic * 8192 + bz * kN + j0 + 16 * w + q8 * 4 + r] = lloc[r];
    }
}

// ---------------------------------------------------------------------------
// out (round-2 measured-best form + count==0 early exit):
// partial[i,h] = sum_{j in jc-chunk, j<=i} (exp(s/8)/l[j]) * v[j,h]
// vsm g2l double-buffered; K fragments in registers; Q direct + reg prefetch;
// 1/l folded into P; LDS 29.7 KB.
// ---------------------------------------------------------------------------
__global__ __launch_bounds__(256) void out_kernel(
        const short* __restrict__ gq, const short* __restrict__ gk,
        const short* __restrict__ vt, const float* __restrict__ l2,
        float* __restrict__ part)
{
    __shared__ __align__(16) short vsm[2][64 * 72];
    __shared__ __align__(16) short psm[64 * 72];
    __shared__ __align__(16) float rsm[512];
    const int t = threadIdx.x;
    const int w = t >> 6, lane = t & 63, l15 = lane & 15, q8 = lane >> 4;
    const int b = blockIdx.x;
    const int jc = b & 3, bz = (b >> 2) & 3, it = b >> 4;
    const int i0 = it * 64;
    const int jlo = jc * 512;
    const int jhi = (jlo + 512 < i0 + 64) ? (jlo + 512) : (i0 + 64);
    const int count = (jlo < jhi) ? ((jhi - jlo) >> 6) : 0;
    if (count == 0) return;    // block-uniform; reduce skips this slice

    // reciprocal softmax denominators for this block's j-range (512 entries)
    for (int jj = t; jj < 512; jj += 256) {
        int j = bz * kN + jlo + jj;
        float l = l2[j] + l2[8192 + j] + l2[16384 + j] + l2[24576 + j];
        rsm[jj] = (l > 0.f) ? 1.0f / l : 0.0f;
    }

    f32x4 oacc[4];
    #pragma unroll
    for (int i = 0; i < 4; ++i) oacc[i] = (f32x4){0.f, 0.f, 0.f, 0.f};

    // K fragments: loop-invariant for the whole block -> registers
    bf16x8 kb0[4], kb1[4];
    #pragma unroll
    for (int itile = 0; itile < 4; ++itile) {
        const short* kp = gk + (size_t)(bz * kN + i0 + itile * 16 + l15) * 72 + q8 * 8;
        kb0[itile] = *(const bf16x8*)kp;
        kb1[itile] = *(const bf16x8*)(kp + 32);
    }
    g2l(vsm[0], vt + (size_t)((bz * 32 + (jlo >> 6)) * 64) * 72, 64 * 144, t);
    const short* qp = gq + (size_t)(bz * kN + jlo + 16 * w + l15) * 72 + q8 * 8;
    bf16x8 qa0 = *(const bf16x8*)qp;
    bf16x8 qa1 = *(const bf16x8*)(qp + 32);
    __syncthreads();       // vsm[0] staged, rsm ready

    for (int idx = 0; idx < count; ++idx) {
        const int cur = idx & 1, nb = cur ^ 1;
        const int j0s = jlo + idx * 64;
        const bool more = (idx + 1 < count);
        bf16x8 qn0, qn1;
        if (more) {
            g2l(vsm[nb], vt + (size_t)((bz * 32 + ((j0s + 64) >> 6)) * 64) * 72,
                64 * 144, t);
            const short* qn =
                gq + (size_t)(bz * kN + j0s + 64 + 16 * w + l15) * 72 + q8 * 8;
            qn0 = *(const bf16x8*)qn;
            qn1 = *(const bf16x8*)(qn + 32);
        }
        // rl for this iteration's 4 j's (broadcast within 16-lane groups)
        f32x4 rl4 = *(const f32x4*)&rsm[(j0s - jlo) + 16 * w + q8 * 4];

        // S phase (bit-identical MFMA sequence to stats)
        #pragma unroll
        for (int itile = 0; itile < 4; ++itile) {
            f32x4 s = (f32x4){0.f, 0.f, 0.f, 0.f};
            s = MFMA(qa0, kb0[itile], s);
            s = MFMA(qa1, kb1[itile], s);
            int ig = i0 + itile * 16 + l15;
            bf16x4 pk;
            if (i0 + itile * 16 >= j0s + 16 * w + 15) {
                #pragma unroll
                for (int r = 0; r < 4; ++r) {
                    float sv = s[r];
                    float p = (sv != 0.0f) ? EXP8(sv) * rl4[r] : 0.0f;
                    pk[r] = f2bf(p);
                }
            } else {
                #pragma unroll
                for (int r = 0; r < 4; ++r) {
                    int jg = j0s + 16 * w + q8 * 4 + r;
                    float sv = s[r];
                    float p = ((ig >= jg) && (sv != 0.0f))
                              ? EXP8(sv) * rl4[r] : 0.0f;
                    pk[r] = f2bf(p);
                }
            }
            *(bf16x4*)&psm[(itile * 16 + l15) * 72 + 16 * w + q8 * 4] = pk;
        }
        __syncthreads();   // psm ready; prefetches had the S phase to fly

        // PV phase: A = psm[i-local][j], B = vsm[h][j] (unscaled v)
        bf16x8 pa0 = *(const bf16x8*)&psm[(16 * w + l15) * 72 + q8 * 8];
        bf16x8 pa1 = *(const bf16x8*)&psm[(16 * w + l15) * 72 + 32 + q8 * 8];
        #pragma unroll
        for (int ht = 0; ht < 4; ++ht) {
            int vrow = ht * 16 + l15;
            bf16x8 vb0 = *(const bf16x8*)&vsm[cur][vrow * 72 + q8 * 8];
            bf16x8 vb1 = *(const bf16x8*)&vsm[cur][vrow * 72 + 32 + q8 * 8];
            oacc[ht] = MFMA(pa0, vb0, oacc[ht]);
            oacc[ht] = MFMA(pa1, vb1, oacc[ht]);
        }
        __syncthreads();   // protect psm + vsm[cur] before next overwrite
        if (more) { qa0 = qn0; qa1 = qn1; }
    }

    size_t base = ((size_t)(jc * 4 + bz) * kN + i0) * 64;
    #pragma unroll
    for (int ht = 0; ht < 4; ++ht)
        #pragma unroll
        for (int r = 0; r < 4; ++r)
            part[base + (size_t)(16 * w + q8 * 4 + r) * 64 + ht * 16 + l15] = oacc[ht][r];
}

// ---------------------------------------------------------------------------
// reduce: out = sum of the VALID jc-chunk partials only.
// Chunk jc valid for row i iff jc < (i>>9)+1 (matches out's count>0 set).
// ---------------------------------------------------------------------------
__global__ __launch_bounds__(256) void reduce_kernel(
        const float* __restrict__ part, float* __restrict__ out)
{
    int idx = blockIdx.x * 256 + threadIdx.x;     // 0..131071 float4s
    int i = (idx >> 4) & 2047;                    // row within [bz][2048][64]
    int nvalid = (i >> 9) + 1;                    // 1..4
    const float4* p = (const float4*)part;
    float4 r = p[idx];
    for (int c = 1; c < nvalid; ++c) {
        float4 v = p[idx + c * 131072];
        r.x += v.x; r.y += v.y; r.z += v.z; r.w += v.w;
    }
    ((float4*)out)[idx] = r;
}

extern "C" void kernel_launch(void* const* d_in, const int* in_sizes, int n_in,
                              void* d_out, int out_size, void* d_ws, size_t ws_size,
                              hipStream_t stream)
{
    const float* x  = (const float*)d_in[0];
    const float* Wq = (const float*)d_in[1];
    const float* bq = (const float*)d_in[2];
    const float* Wk = (const float*)d_in[3];
    const float* bk = (const float*)d_in[4];
    const float* Wv = (const float*)d_in[5];
    const float* bv = (const float*)d_in[6];
    float* out = (float*)d_out;

    char* base = (char*)d_ws;
    short* Wt   = (short*)(base);                    //    393,216 B
    float* bcat = (float*)(base + 393216);           //      1,024 B
    short* gq   = (short*)(base + 394240);           //  1,179,648 B
    short* gk   = (short*)(base + 1573888);          //  1,179,648 B
    short* vt   = (short*)(base + 2753536);          //  1,179,648 B
    float* l2   = (float*)(base + 3933184);          //    131,072 B
    float* part = (float*)(base + 4064256);          //  8,388,608 B

    prep_kernel<<<192, 256, 0, stream>>>(Wq, Wk, Wv, bq, bk, bv, Wt, bcat);
    qkv_kernel<<<512, 256, 0, stream>>>(x, Wt, bcat, gq, gk, vt);
    stats_kernel<<<512, 256, 0, stream>>>(gq, gk, l2);
    out_kernel<<<512, 256, 0, stream>>>(gq, gk, vt, l2, part);
    reduce_kernel<<<512, 256, 0, stream>>>(part, out);
}